// Round 13
// baseline (83.091 us; speedup 1.0000x reference)
//
#include <hip/hip_runtime.h>

// SparseProductLayer:  out = x @ (M0*M1*M2)^T + bias
// Pipeline: zero -> fused xconv+hist (4096+192 blocks) -> scan -> scatter ->
// mcbuild -> 4-phase fine-interleaved MFMA GEMM (m201-style): BM=128,BN=256,
// BK=64, 3-slot LDS ring, per phase {ds_read subtile | stage units | 2 bars |
// lgkmcnt(0) | 8 MFMA}, vmcnt(6) once per K-step, chunk^row&7 swizzle,
// setprio. 256 blocks = 1/CU.

#define BATCH 4096
#define DIM   2048
#define NNZc  16384
#define NT    256

typedef short bf16x8 __attribute__((ext_vector_type(8)));
typedef float f32x4  __attribute__((ext_vector_type(4)));

__device__ __forceinline__ unsigned short f2bf(float f) {
    unsigned u = __float_as_uint(f);
    unsigned r = (u + 0x7fffu + ((u >> 16) & 1u)) >> 16;   // RNE
    return (unsigned short)r;
}

__device__ __forceinline__ void gload16(const void* g, void* l) {
    __builtin_amdgcn_global_load_lds((const __attribute__((address_space(1))) void*)g,
                                     (__attribute__((address_space(3))) void*)l, 16, 0, 0);
}

// ---- zero the 3*2048 counters ----
__global__ void zero_kernel(int* __restrict__ p) {
    int i = blockIdx.x * NT + threadIdx.x;
    if (i < 3 * DIM) p[i] = 0;
}

// ---- fused: xconv (blocks 0..4095) + histogram (blocks 4096..4287) ----
#define XCONV_BLKS (BATCH * DIM / (NT * 8))     // 4096
__global__ void histxconv_kernel(const float* __restrict__ x, unsigned short* __restrict__ Xb,
                                 const int* __restrict__ rows0, const int* __restrict__ rows1,
                                 const int* __restrict__ rows2, int* __restrict__ cur) {
    int bid = blockIdx.x;
    if (bid < XCONV_BLKS) {
        size_t i = ((size_t)bid * NT + threadIdx.x) * 8;
        float4 a = *(const float4*)(x + i);
        float4 b = *(const float4*)(x + i + 4);
        unsigned short o[8] = {f2bf(a.x), f2bf(a.y), f2bf(a.z), f2bf(a.w),
                               f2bf(b.x), f2bf(b.y), f2bf(b.z), f2bf(b.w)};
        *(ulonglong2*)(Xb + i) = *(ulonglong2*)o;
    } else {
        int e = (bid - XCONV_BLKS) * NT + threadIdx.x;   // 0 .. 3*NNZ
        int m = e >> 14, i = e & (NNZc - 1);
        const int* rp = (m == 0) ? rows0 : (m == 1) ? rows1 : rows2;
        atomicAdd(&cur[m * DIM + rp[i]], 1);
    }
}

// ---- CSR build: exclusive scan of 2048 counts (parallel shuffle scan) ----
__global__ void scan_kernel(int* __restrict__ curb, int* __restrict__ offb) {
    int* cur = curb + blockIdx.x * DIM;
    int* off = offb + blockIdx.x * 2052;
    __shared__ int wsum[4];
    int t = threadIdx.x;
    int c[8]; int s = 0;
    #pragma unroll
    for (int i = 0; i < 8; ++i) { c[i] = cur[t * 8 + i]; s += c[i]; }
    int l = t & 63, wv = t >> 6;
    int v = s;
    #pragma unroll
    for (int d = 1; d < 64; d <<= 1) {
        int u = __shfl_up(v, d, 64);
        if (l >= d) v += u;
    }
    if (l == 63) wsum[wv] = v;
    __syncthreads();
    int wbase = 0;
    for (int i = 0; i < wv; ++i) wbase += wsum[i];
    int base = wbase + v - s;
    #pragma unroll
    for (int i = 0; i < 8; ++i) {
        int idx = t * 8 + i;
        off[idx] = base; cur[idx] = base; base += c[i];
    }
    if (t == 0) off[DIM] = NNZc;
}

// ---- CSR build: scatter entries into row buckets ----
__global__ void scatter_kernel(const int* __restrict__ rows0, const int* __restrict__ cols0,
                               const float* __restrict__ vals0,
                               const int* __restrict__ rows1, const int* __restrict__ cols1,
                               const float* __restrict__ vals1,
                               const int* __restrict__ rows2, const int* __restrict__ cols2,
                               const float* __restrict__ vals2,
                               int* __restrict__ cur,
                               int* __restrict__ colb, float* __restrict__ valb) {
    int e = blockIdx.x * NT + threadIdx.x;
    int m = e >> 14, i = e & (NNZc - 1);
    const int*   rp = (m == 0) ? rows0 : (m == 1) ? rows1 : rows2;
    const int*   cp = (m == 0) ? cols0 : (m == 1) ? cols1 : cols2;
    const float* vp = (m == 0) ? vals0 : (m == 1) ? vals1 : vals2;
    int slot = atomicAdd(&cur[m * DIM + rp[i]], 1);
    colb[m * NNZc + slot] = cp[i];
    valb[m * NNZc + slot] = vp[i];
}

// ---- Mc build: per block, RPB output rows via 3-level tree walk in LDS ----
#define RPB  2
#define PCAP 2048
__global__ __launch_bounds__(NT) void mcbuild_kernel(
        const int* __restrict__ offb, const int* __restrict__ colb,
        const float* __restrict__ valb, unsigned short* __restrict__ Mc) {
    const int* off0 = offb;              const int* off1 = offb + 2052;  const int* off2 = offb + 4104;
    const int* col0 = colb;              const int* col1 = colb + NNZc;  const int* col2 = colb + 2 * NNZc;
    const float* val0 = valb;            const float* val1 = valb + NNZc; const float* val2 = valb + 2 * NNZc;

    __shared__ float acc[RPB * DIM];
    __shared__ int   pk[PCAP];
    __shared__ float pw[PCAP];
    __shared__ int   npairs;

    const int tid = threadIdx.x;
    const int r0  = blockIdx.x * RPB;

    f32x4* az = (f32x4*)acc;
    #pragma unroll
    for (int j = tid; j < RPB * DIM / 4; j += NT) az[j] = (f32x4){0.f, 0.f, 0.f, 0.f};
    if (tid == 0) npairs = 0;
    __syncthreads();

    #pragma unroll
    for (int k = 0; k < RPB; ++k) {
        int b = off0[r0 + k], e = off0[r0 + k + 1];
        for (int i = b + tid; i < e; i += NT) {
            int   c0 = col0[i];
            float v0 = val0[i];
            int b1 = off1[c0], e1 = off1[c0 + 1];
            for (int j = b1; j < e1; ++j) {
                float w = v0 * val1[j];
                int   c1 = col1[j];
                int slot = atomicAdd(&npairs, 1);
                if (slot < PCAP) { pk[slot] = (k << 16) | c1; pw[slot] = w; }
                else {
                    int b2 = off2[c1], e2 = off2[c1 + 1];
                    for (int q = b2; q < e2; ++q)
                        atomicAdd(&acc[k * DIM + col2[q]], w * val2[q]);
                }
            }
        }
    }
    __syncthreads();

    int np = min(npairs, PCAP);
    for (int p = tid; p < np; p += NT) {
        int   k  = pk[p] >> 16, c1 = pk[p] & 0xffff;
        float w  = pw[p];
        int b2 = off2[c1], e2 = off2[c1 + 1];
        for (int q = b2; q < e2; ++q)
            atomicAdd(&acc[k * DIM + col2[q]], w * val2[q]);
    }
    __syncthreads();

    #pragma unroll
    for (int k = 0; k < RPB; ++k) {
        unsigned short o[8];
        #pragma unroll
        for (int jj = 0; jj < 8; ++jj) o[jj] = f2bf(acc[k * DIM + tid * 8 + jj]);
        *(ulonglong2*)(Mc + (size_t)(r0 + k) * DIM + tid * 8) = *(ulonglong2*)o;
    }
}

// ---- GEMM: C = Xb(4096x2048) @ Mc^T + bias ----
// 3-slot ring, BK=64, slot = A[128][64] + B[256][64], swizzle chunk^(row&7).
// 4 phases per K-step: each {ds_read subtile | stage 1-2 units | barrier |
// lgkmcnt(0) | 8 MFMA (one acc column) | barrier}. vmcnt(6) at phase 3 only.
#define BM 128
#define BN 256
#define BK 64
#define NS (DIM / BK)                   // 32
#define A_SL (BM * BK * 2)              // 16384
#define B_SL (BN * BK * 2)              // 32768
#define SLOT (A_SL + B_SL)              // 49152
#define GEMM_LDS (3 * SLOT)             // 147456

__global__ __launch_bounds__(512, 2) void gemm8(
        const unsigned short* __restrict__ A,   // Xb [4096][2048]
        const unsigned short* __restrict__ Bm,  // Mc [2048][2048]
        const float* __restrict__ bias,
        float* __restrict__ C) {
    extern __shared__ char smem[];
    const int tid = threadIdx.x;
    const int l = tid & 63, w = tid >> 6;
    const int wm = w & 1, wn = w >> 1;          // 2M x 4N wave grid, tile 64x64
    const int tileM = blockIdx.y * BM;
    const int tileN = blockIdx.x * BN;

    // staging: lane l covers row-in-8 (l>>3), phys chunk l&7; source pre-swizzled
    const int r8   = l >> 3;
    const int clog = (l & 7) ^ r8;
    const unsigned short* aS0 = A  + (size_t)(tileM + 8 * w + r8) * DIM + clog * 8;
    const unsigned short* aS1 = aS0 + (size_t)64 * DIM;
    const unsigned short* bS0 = Bm + (size_t)(tileN + 32 * w + r8) * DIM + clog * 8;

#define SU0(z, s) gload16(aS0 +            (size_t)(s) * BK, (z) + w * 1024)
#define SU1(z, s) gload16(aS1 +            (size_t)(s) * BK, (z) + 8192 + w * 1024)
#define SU2(z, s) gload16(bS0 +            (size_t)(s) * BK, (z) + A_SL + w * 4096)
#define SU3(z, s) gload16(bS0 +  8 * DIM + (size_t)(s) * BK, (z) + A_SL + w * 4096 + 1024)
#define SU4(z, s) gload16(bS0 + 16 * DIM + (size_t)(s) * BK, (z) + A_SL + w * 4096 + 2048)
#define SU5(z, s) gload16(bS0 + 24 * DIM + (size_t)(s) * BK, (z) + A_SL + w * 4096 + 3072)

    // frag read offsets: row (l&15), k-chunks swizzled by l&7
    const int rbyte = (l & 15) * 128;
    const int kc0 = (((l >> 4)    ) ^ (l & 7)) * 16;
    const int kc1 = (((l >> 4) + 4) ^ (l & 7)) * 16;

#define PHASE_BAR() do {                                      \
    __builtin_amdgcn_sched_barrier(0);                        \
    __builtin_amdgcn_s_barrier();                             \
    asm volatile("s_waitcnt lgkmcnt(0)" ::: "memory");        \
    __builtin_amdgcn_sched_barrier(0);                        \
} while (0)

#define MFMA_COL(jj) do {                                                              \
    __builtin_amdgcn_s_setprio(1);                                                     \
    _Pragma("unroll")                                                                  \
    for (int _q = 0; _q < 4; ++_q) {                                                   \
        acc[_q][jj] = __builtin_amdgcn_mfma_f32_16x16x32_bf16(A0[_q], B0,              \
                                                              acc[_q][jj], 0, 0, 0);   \
        acc[_q][jj] = __builtin_amdgcn_mfma_f32_16x16x32_bf16(A1[_q], B1,              \
                                                              acc[_q][jj], 0, 0, 0);   \
    }                                                                                  \
    __builtin_amdgcn_s_setprio(0);                                                     \
} while (0)

    bf16x8 A0[4], A1[4], B0, B1;
    f32x4 acc[4][4] = {};

    char* p0 = smem;
    char* p1 = smem + SLOT;
    char* p2 = smem + 2 * SLOT;

    // prologue: stage steps 0 and 1 fully; wait step0 landed (6 in flight)
    SU0(p0, 0); SU1(p0, 0); SU2(p0, 0); SU3(p0, 0); SU4(p0, 0); SU5(p0, 0);
    SU0(p1, 1); SU1(p1, 1); SU2(p1, 1); SU3(p1, 1); SU4(p1, 1); SU5(p1, 1);
    asm volatile("s_waitcnt vmcnt(6)" ::: "memory");
    __builtin_amdgcn_sched_barrier(0);
    __builtin_amdgcn_s_barrier();

    for (int s = 0; s < NS; ++s) {
        const bool pf = (s + 2 < NS);
        const char* ab = p0 + wm * 8192 + rbyte;
        const char* bb = p0 + A_SL + wn * 8192 + rbyte;

        // ---- phase 0: all A frags + B col 0; stage units 0,1 ----
        #pragma unroll
        for (int q = 0; q < 4; ++q) {
            A0[q] = *(const bf16x8*)(ab + q * 2048 + kc0);
            A1[q] = *(const bf16x8*)(ab + q * 2048 + kc1);
        }
        B0 = *(const bf16x8*)(bb + kc0);
        B1 = *(const bf16x8*)(bb + kc1);
        if (pf) { SU0(p2, s + 2); SU1(p2, s + 2); }
        PHASE_BAR();
        MFMA_COL(0);
        __builtin_amdgcn_s_barrier();

        // ---- phase 1: B col 1; stage units 2,3 ----
        B0 = *(const bf16x8*)(bb + 1 * 2048 + kc0);
        B1 = *(const bf16x8*)(bb + 1 * 2048 + kc1);
        if (pf) { SU2(p2, s + 2); SU3(p2, s + 2); }
        PHASE_BAR();
        MFMA_COL(1);
        __builtin_amdgcn_s_barrier();

        // ---- phase 2: B col 2; stage unit 4 ----
        B0 = *(const bf16x8*)(bb + 2 * 2048 + kc0);
        B1 = *(const bf16x8*)(bb + 2 * 2048 + kc1);
        if (pf) { SU4(p2, s + 2); }
        PHASE_BAR();
        MFMA_COL(2);
        __builtin_amdgcn_s_barrier();

        // ---- phase 3: B col 3; stage unit 5; counted vmcnt ----
        B0 = *(const bf16x8*)(bb + 3 * 2048 + kc0);
        B1 = *(const bf16x8*)(bb + 3 * 2048 + kc1);
        if (pf) { SU5(p2, s + 2); }
        PHASE_BAR();
        MFMA_COL(3);
        __builtin_amdgcn_sched_barrier(0);
        if (pf) asm volatile("s_waitcnt vmcnt(6)" ::: "memory");
        else    asm volatile("s_waitcnt vmcnt(0)" ::: "memory");
        __builtin_amdgcn_sched_barrier(0);
        __builtin_amdgcn_s_barrier();

        char* t = p0; p0 = p1; p1 = p2; p2 = t;
    }

    // ---- epilogue: C = acc + bias ----
    #pragma unroll
    for (int j = 0; j < 4; ++j) {
        int col = tileN + wn * 64 + j * 16 + (l & 15);
        float bj = bias[col];
        #pragma unroll
        for (int i = 0; i < 4; ++i) {
            int rw = tileM + wm * 64 + i * 16 + (l >> 4) * 4;
            #pragma unroll
            for (int r = 0; r < 4; ++r)
                C[(size_t)(rw + r) * DIM + col] = acc[i][j][r] + bj;
        }
    }
}

extern "C" void kernel_launch(void* const* d_in, const int* in_sizes, int n_in,
                              void* d_out, int out_size, void* d_ws, size_t ws_size,
                              hipStream_t stream) {
    const float* x     = (const float*)d_in[0];
    const int*   rows0 = (const int*)  d_in[1];
    const int*   cols0 = (const int*)  d_in[2];
    const float* vals0 = (const float*)d_in[3];
    const int*   rows1 = (const int*)  d_in[4];
    const int*   cols1 = (const int*)  d_in[5];
    const float* vals1 = (const float*)d_in[6];
    const int*   rows2 = (const int*)  d_in[7];
    const int*   cols2 = (const int*)  d_in[8];
    const float* vals2 = (const float*)d_in[9];
    const float* bias  = (const float*)d_in[10];
    float* out = (float*)d_out;

    char* ws = (char*)d_ws;
    unsigned short* Mc = (unsigned short*)ws;                 // 8 MB
    unsigned short* Xb = (unsigned short*)(ws + 8388608);     // 16 MB
    int*   offb = (int*)(ws + 25165824);      // 3 * 2052
    int*   curb = offb + 3 * 2052;            // 3 * 2048
    int*   colb = curb + 3 * DIM;             // 3 * 16384
    float* valb = (float*)(colb + 3 * NNZc);  // 3 * 16384

    zero_kernel<<<(3 * DIM + NT - 1) / NT, NT, 0, stream>>>(curb);
    histxconv_kernel<<<XCONV_BLKS + 3 * NNZc / NT, NT, 0, stream>>>(x, Xb,
                                                                    rows0, rows1, rows2, curb);
    scan_kernel<<<3, NT, 0, stream>>>(curb, offb);
    scatter_kernel<<<3 * NNZc / NT, NT, 0, stream>>>(rows0, cols0, vals0,
                                                     rows1, cols1, vals1,
                                                     rows2, cols2, vals2,
                                                     curb, colb, valb);
    mcbuild_kernel<<<DIM / RPB, NT, 0, stream>>>(offb, colb, valb, Mc);

    (void)hipFuncSetAttribute((const void*)gemm8,
                              hipFuncAttributeMaxDynamicSharedMemorySize, GEMM_LDS);
    dim3 ggrid(DIM / BN, BATCH / BM);   // 8 x 32 = 256 blocks
    gemm8<<<ggrid, 512, GEMM_LDS, stream>>>(Xb, Mc, bias, out);
}

// Round 14
// 76.551 us; speedup vs baseline: 1.0854x; 1.0854x over previous
//
#include <hip/hip_runtime.h>

// SparseProductLayer:  out = x @ (M0*M1*M2)^T + bias
// Pipeline: zero -> fused xconv+hist -> scan -> scatter -> mcbuild ->
// MFMA GEMM (r10 core: BM=128,BN=256,BK=64, 3-slot ring, 1 barrier/step,
// vmcnt(6), pinned frag dbuf, chunk^row&7 swizzle, setprio)
// + XCD-chunked block swizzle: each XCD gets an 8y x 4x region.

#define BATCH 4096
#define DIM   2048
#define NNZc  16384
#define NT    256

typedef short bf16x8 __attribute__((ext_vector_type(8)));
typedef float f32x4  __attribute__((ext_vector_type(4)));

__device__ __forceinline__ unsigned short f2bf(float f) {
    unsigned u = __float_as_uint(f);
    unsigned r = (u + 0x7fffu + ((u >> 16) & 1u)) >> 16;   // RNE
    return (unsigned short)r;
}

__device__ __forceinline__ void gload16(const void* g, void* l) {
    __builtin_amdgcn_global_load_lds((const __attribute__((address_space(1))) void*)g,
                                     (__attribute__((address_space(3))) void*)l, 16, 0, 0);
}

// ---- zero the 3*2048 counters ----
__global__ void zero_kernel(int* __restrict__ p) {
    int i = blockIdx.x * NT + threadIdx.x;
    if (i < 3 * DIM) p[i] = 0;
}

// ---- fused: xconv (blocks 0..4095) + histogram (blocks 4096..4287) ----
#define XCONV_BLKS (BATCH * DIM / (NT * 8))     // 4096
__global__ void histxconv_kernel(const float* __restrict__ x, unsigned short* __restrict__ Xb,
                                 const int* __restrict__ rows0, const int* __restrict__ rows1,
                                 const int* __restrict__ rows2, int* __restrict__ cur) {
    int bid = blockIdx.x;
    if (bid < XCONV_BLKS) {
        size_t i = ((size_t)bid * NT + threadIdx.x) * 8;
        float4 a = *(const float4*)(x + i);
        float4 b = *(const float4*)(x + i + 4);
        unsigned short o[8] = {f2bf(a.x), f2bf(a.y), f2bf(a.z), f2bf(a.w),
                               f2bf(b.x), f2bf(b.y), f2bf(b.z), f2bf(b.w)};
        *(ulonglong2*)(Xb + i) = *(ulonglong2*)o;
    } else {
        int e = (bid - XCONV_BLKS) * NT + threadIdx.x;   // 0 .. 3*NNZ
        int m = e >> 14, i = e & (NNZc - 1);
        const int* rp = (m == 0) ? rows0 : (m == 1) ? rows1 : rows2;
        atomicAdd(&cur[m * DIM + rp[i]], 1);
    }
}

// ---- CSR build: exclusive scan of 2048 counts (parallel shuffle scan) ----
__global__ void scan_kernel(int* __restrict__ curb, int* __restrict__ offb) {
    int* cur = curb + blockIdx.x * DIM;
    int* off = offb + blockIdx.x * 2052;
    __shared__ int wsum[4];
    int t = threadIdx.x;
    int c[8]; int s = 0;
    #pragma unroll
    for (int i = 0; i < 8; ++i) { c[i] = cur[t * 8 + i]; s += c[i]; }
    int l = t & 63, wv = t >> 6;
    int v = s;
    #pragma unroll
    for (int d = 1; d < 64; d <<= 1) {
        int u = __shfl_up(v, d, 64);
        if (l >= d) v += u;
    }
    if (l == 63) wsum[wv] = v;
    __syncthreads();
    int wbase = 0;
    for (int i = 0; i < wv; ++i) wbase += wsum[i];
    int base = wbase + v - s;
    #pragma unroll
    for (int i = 0; i < 8; ++i) {
        int idx = t * 8 + i;
        off[idx] = base; cur[idx] = base; base += c[i];
    }
    if (t == 0) off[DIM] = NNZc;
}

// ---- CSR build: scatter entries into row buckets ----
__global__ void scatter_kernel(const int* __restrict__ rows0, const int* __restrict__ cols0,
                               const float* __restrict__ vals0,
                               const int* __restrict__ rows1, const int* __restrict__ cols1,
                               const float* __restrict__ vals1,
                               const int* __restrict__ rows2, const int* __restrict__ cols2,
                               const float* __restrict__ vals2,
                               int* __restrict__ cur,
                               int* __restrict__ colb, float* __restrict__ valb) {
    int e = blockIdx.x * NT + threadIdx.x;
    int m = e >> 14, i = e & (NNZc - 1);
    const int*   rp = (m == 0) ? rows0 : (m == 1) ? rows1 : rows2;
    const int*   cp = (m == 0) ? cols0 : (m == 1) ? cols1 : cols2;
    const float* vp = (m == 0) ? vals0 : (m == 1) ? vals1 : vals2;
    int slot = atomicAdd(&cur[m * DIM + rp[i]], 1);
    colb[m * NNZc + slot] = cp[i];
    valb[m * NNZc + slot] = vp[i];
}

// ---- Mc build: per block, RPB output rows via 3-level tree walk in LDS ----
#define RPB  2
#define PCAP 2048
__global__ __launch_bounds__(NT) void mcbuild_kernel(
        const int* __restrict__ offb, const int* __restrict__ colb,
        const float* __restrict__ valb, unsigned short* __restrict__ Mc) {
    const int* off0 = offb;              const int* off1 = offb + 2052;  const int* off2 = offb + 4104;
    const int* col0 = colb;              const int* col1 = colb + NNZc;  const int* col2 = colb + 2 * NNZc;
    const float* val0 = valb;            const float* val1 = valb + NNZc; const float* val2 = valb + 2 * NNZc;

    __shared__ float acc[RPB * DIM];
    __shared__ int   pk[PCAP];
    __shared__ float pw[PCAP];
    __shared__ int   npairs;

    const int tid = threadIdx.x;
    const int r0  = blockIdx.x * RPB;

    f32x4* az = (f32x4*)acc;
    #pragma unroll
    for (int j = tid; j < RPB * DIM / 4; j += NT) az[j] = (f32x4){0.f, 0.f, 0.f, 0.f};
    if (tid == 0) npairs = 0;
    __syncthreads();

    #pragma unroll
    for (int k = 0; k < RPB; ++k) {
        int b = off0[r0 + k], e = off0[r0 + k + 1];
        for (int i = b + tid; i < e; i += NT) {
            int   c0 = col0[i];
            float v0 = val0[i];
            int b1 = off1[c0], e1 = off1[c0 + 1];
            for (int j = b1; j < e1; ++j) {
                float w = v0 * val1[j];
                int   c1 = col1[j];
                int slot = atomicAdd(&npairs, 1);
                if (slot < PCAP) { pk[slot] = (k << 16) | c1; pw[slot] = w; }
                else {
                    int b2 = off2[c1], e2 = off2[c1 + 1];
                    for (int q = b2; q < e2; ++q)
                        atomicAdd(&acc[k * DIM + col2[q]], w * val2[q]);
                }
            }
        }
    }
    __syncthreads();

    int np = min(npairs, PCAP);
    for (int p = tid; p < np; p += NT) {
        int   k  = pk[p] >> 16, c1 = pk[p] & 0xffff;
        float w  = pw[p];
        int b2 = off2[c1], e2 = off2[c1 + 1];
        for (int q = b2; q < e2; ++q)
            atomicAdd(&acc[k * DIM + col2[q]], w * val2[q]);
    }
    __syncthreads();

    #pragma unroll
    for (int k = 0; k < RPB; ++k) {
        unsigned short o[8];
        #pragma unroll
        for (int jj = 0; jj < 8; ++jj) o[jj] = f2bf(acc[k * DIM + tid * 8 + jj]);
        *(ulonglong2*)(Mc + (size_t)(r0 + k) * DIM + tid * 8) = *(ulonglong2*)o;
    }
}

// ---- GEMM: C = Xb(4096x2048) @ Mc^T + bias ----
// r10 core. 3-slot ring, BK=64, slot = A[128][64] + B[256][64] (128-B rows),
// swizzle chunk^(row&7). Per step/wave: 6 gload_lds (stage s+2) + 16
// ds_read_b128 (frags s+1, pinned) + 32 MFMA. One barrier/step, vmcnt(6).
// XCD-chunked block swizzle: xcd k=(bid&7) owns y in [ (k>>1)*8, +8 ),
// x in [ (k&1)*4, +4 ) -- 8MB working set per XCD instead of 17MB.
#define BM 128
#define BN 256
#define BK 64
#define NS (DIM / BK)                   // 32
#define A_SL (BM * BK * 2)              // 16384
#define B_SL (BN * BK * 2)              // 32768
#define SLOT (A_SL + B_SL)              // 49152
#define GEMM_LDS (3 * SLOT)             // 147456

__global__ __launch_bounds__(512, 2) void gemm8(
        const unsigned short* __restrict__ A,   // Xb [4096][2048]
        const unsigned short* __restrict__ Bm,  // Mc [2048][2048]
        const float* __restrict__ bias,
        float* __restrict__ C) {
    extern __shared__ char smem[];
    const int tid = threadIdx.x;
    const int l = tid & 63, w = tid >> 6;
    const int wm = w & 1, wn = w >> 1;          // 2M x 4N wave grid, tile 64x64

    // XCD-chunked swizzle: bid -> (ty, tx); xcd = bid & 7 (round-robin default)
    const int bid = blockIdx.x;
    const int k = bid & 7, c = bid >> 3;
    const int tileM = ((k >> 1) * 8 + (c >> 2)) * BM;   // ty in [0,32)
    const int tileN = ((k & 1) * 4 + (c & 3)) * BN;     // tx in [0,8)

    // staging: lane l covers row-in-8 (l>>3), phys chunk l&7; source pre-swizzled
    const int r8   = l >> 3;
    const int clog = (l & 7) ^ r8;
    const unsigned short* aS0 = A  + (size_t)(tileM + 8 * w + r8) * DIM + clog * 8;
    const unsigned short* aS1 = aS0 + (size_t)64 * DIM;
    const unsigned short* bS0 = Bm + (size_t)(tileN + 32 * w + r8) * DIM + clog * 8;

#define STAGE(z, s) do {                                                   \
    gload16(aS0 +                (size_t)(s) * BK, (z) + w * 1024);        \
    gload16(aS1 +                (size_t)(s) * BK, (z) + 8192 + w * 1024); \
    gload16(bS0 +                (size_t)(s) * BK, (z) + A_SL + w * 4096);        \
    gload16(bS0 +  8 * DIM +     (size_t)(s) * BK, (z) + A_SL + w * 4096 + 1024); \
    gload16(bS0 + 16 * DIM +     (size_t)(s) * BK, (z) + A_SL + w * 4096 + 2048); \
    gload16(bS0 + 24 * DIM +     (size_t)(s) * BK, (z) + A_SL + w * 4096 + 3072); \
} while (0)

    // frag read offsets: row (l&15), k-chunks swizzled by l&7
    const int rbyte = (l & 15) * 128;
    const int c0 = (((l >> 4)    ) ^ (l & 7)) * 16;   // ks=0
    const int c1 = (((l >> 4) + 4) ^ (l & 7)) * 16;   // ks=1

#define LOADFRAGS(z, A0, A1, B0, B1) do {                            \
    const char* _ab = (z) + wm * 8192 + rbyte;                       \
    A0[0] = *(const bf16x8*)(_ab + 0 * 2048 + c0);                   \
    A1[0] = *(const bf16x8*)(_ab + 0 * 2048 + c1);                   \
    A0[1] = *(const bf16x8*)(_ab + 1 * 2048 + c0);                   \
    A1[1] = *(const bf16x8*)(_ab + 1 * 2048 + c1);                   \
    A0[2] = *(const bf16x8*)(_ab + 2 * 2048 + c0);                   \
    A1[2] = *(const bf16x8*)(_ab + 2 * 2048 + c1);                   \
    A0[3] = *(const bf16x8*)(_ab + 3 * 2048 + c0);                   \
    A1[3] = *(const bf16x8*)(_ab + 3 * 2048 + c1);                   \
    const char* _bb = (z) + A_SL + wn * 8192 + rbyte;                \
    B0[0] = *(const bf16x8*)(_bb + 0 * 2048 + c0);                   \
    B1[0] = *(const bf16x8*)(_bb + 0 * 2048 + c1);                   \
    B0[1] = *(const bf16x8*)(_bb + 1 * 2048 + c0);                   \
    B1[1] = *(const bf16x8*)(_bb + 1 * 2048 + c1);                   \
    B0[2] = *(const bf16x8*)(_bb + 2 * 2048 + c0);                   \
    B1[2] = *(const bf16x8*)(_bb + 2 * 2048 + c1);                   \
    B0[3] = *(const bf16x8*)(_bb + 3 * 2048 + c0);                   \
    B1[3] = *(const bf16x8*)(_bb + 3 * 2048 + c1);                   \
} while (0)

#define PIN(X) asm volatile("" : "+v"(X[0]), "+v"(X[1]), "+v"(X[2]), "+v"(X[3]))

#define MFMA32(A0, A1, B0, B1) do {                                                    \
    _Pragma("unroll")                                                                  \
    for (int _q = 0; _q < 4; ++_q)                                                     \
        _Pragma("unroll")                                                              \
        for (int _j = 0; _j < 4; ++_j) {                                               \
            acc[_q][_j] = __builtin_amdgcn_mfma_f32_16x16x32_bf16(A0[_q], B0[_j],      \
                                                                  acc[_q][_j], 0,0,0); \
            acc[_q][_j] = __builtin_amdgcn_mfma_f32_16x16x32_bf16(A1[_q], B1[_j],      \
                                                                  acc[_q][_j], 0,0,0); \
        }                                                                              \
} while (0)

    bf16x8 Ae0[4], Ae1[4], Be0[4], Be1[4];
    bf16x8 Ao0[4], Ao1[4], Bo0[4], Bo1[4];
    f32x4 acc[4][4] = {};

    char* p0 = smem;
    char* p1 = smem + SLOT;
    char* p2 = smem + 2 * SLOT;

    // ---- prologue ----
    STAGE(p0, 0);
    STAGE(p1, 1);
    asm volatile("s_waitcnt vmcnt(6)" ::: "memory");   // slot0 landed, stage(1) flying
    __builtin_amdgcn_sched_barrier(0);
    __builtin_amdgcn_s_barrier();
    LOADFRAGS(p0, Ae0, Ae1, Be0, Be1);
    PIN(Ae0); PIN(Ae1); PIN(Be0); PIN(Be1);
    asm volatile("s_waitcnt lgkmcnt(0)" ::: "memory");
    __builtin_amdgcn_sched_barrier(0);

#define BODY(CURA0, CURA1, CURB0, CURB1, NXTA0, NXTA1, NXTB0, NXTB1, S) do {  \
    STAGE(p2, (S) + 2);                                                        \
    __builtin_amdgcn_sched_barrier(0);                                         \
    asm volatile("s_waitcnt vmcnt(6)" ::: "memory");                           \
    __builtin_amdgcn_sched_barrier(0);                                         \
    __builtin_amdgcn_s_barrier();                                              \
    LOADFRAGS(p1, NXTA0, NXTA1, NXTB0, NXTB1);                                 \
    PIN(NXTA0); PIN(NXTA1); PIN(NXTB0); PIN(NXTB1);                            \
    __builtin_amdgcn_sched_barrier(0);                                         \
    __builtin_amdgcn_s_setprio(1);                                             \
    MFMA32(CURA0, CURA1, CURB0, CURB1);                                        \
    __builtin_amdgcn_s_setprio(0);                                             \
    asm volatile("s_waitcnt lgkmcnt(0)" ::: "memory");                         \
    __builtin_amdgcn_sched_barrier(0);                                         \
    { char* _t = p0; p0 = p1; p1 = p2; p2 = _t; }                              \
} while (0)

    // ---- main loop: steps 0..29 as 15 even/odd pairs ----
    for (int t = 0; t < 15; ++t) {
        const int s = 2 * t;
        BODY(Ae0, Ae1, Be0, Be1, Ao0, Ao1, Bo0, Bo1, s);       // step s
        BODY(Ao0, Ao1, Bo0, Bo1, Ae0, Ae1, Be0, Be1, s + 1);   // step s+1
    }
    // ---- tail: step 30 (drain stage(31), read slot31, compute E) ----
    asm volatile("s_waitcnt vmcnt(0)" ::: "memory");
    __builtin_amdgcn_sched_barrier(0);
    __builtin_amdgcn_s_barrier();
    LOADFRAGS(p1, Ao0, Ao1, Bo0, Bo1);
    PIN(Ao0); PIN(Ao1); PIN(Bo0); PIN(Bo1);
    __builtin_amdgcn_sched_barrier(0);
    __builtin_amdgcn_s_setprio(1);
    MFMA32(Ae0, Ae1, Be0, Be1);
    __builtin_amdgcn_s_setprio(0);
    asm volatile("s_waitcnt lgkmcnt(0)" ::: "memory");
    __builtin_amdgcn_sched_barrier(0);
    // step 31
    MFMA32(Ao0, Ao1, Bo0, Bo1);

    // ---- epilogue: C = acc + bias ----
    #pragma unroll
    for (int j = 0; j < 4; ++j) {
        int col = tileN + wn * 64 + j * 16 + (l & 15);
        float bj = bias[col];
        #pragma unroll
        for (int i = 0; i < 4; ++i) {
            int rw = tileM + wm * 64 + i * 16 + (l >> 4) * 4;
            #pragma unroll
            for (int r = 0; r < 4; ++r)
                C[(size_t)(rw + r) * DIM + col] = acc[i][j][r] + bj;
        }
    }
}

extern "C" void kernel_launch(void* const* d_in, const int* in_sizes, int n_in,
                              void* d_out, int out_size, void* d_ws, size_t ws_size,
                              hipStream_t stream) {
    const float* x     = (const float*)d_in[0];
    const int*   rows0 = (const int*)  d_in[1];
    const int*   cols0 = (const int*)  d_in[2];
    const float* vals0 = (const float*)d_in[3];
    const int*   rows1 = (const int*)  d_in[4];
    const int*   cols1 = (const int*)  d_in[5];
    const float* vals1 = (const float*)d_in[6];
    const int*   rows2 = (const int*)  d_in[7];
    const int*   cols2 = (const int*)  d_in[8];
    const float* vals2 = (const float*)d_in[9];
    const float* bias  = (const float*)d_in[10];
    float* out = (float*)d_out;

    char* ws = (char*)d_ws;
    unsigned short* Mc = (unsigned short*)ws;                 // 8 MB
    unsigned short* Xb = (unsigned short*)(ws + 8388608);     // 16 MB
    int*   offb = (int*)(ws + 25165824);      // 3 * 2052
    int*   curb = offb + 3 * 2052;            // 3 * 2048
    int*   colb = curb + 3 * DIM;             // 3 * 16384
    float* valb = (float*)(colb + 3 * NNZc);  // 3 * 16384

    zero_kernel<<<(3 * DIM + NT - 1) / NT, NT, 0, stream>>>(curb);
    histxconv_kernel<<<XCONV_BLKS + 3 * NNZc / NT, NT, 0, stream>>>(x, Xb,
                                                                    rows0, rows1, rows2, curb);
    scan_kernel<<<3, NT, 0, stream>>>(curb, offb);
    scatter_kernel<<<3 * NNZc / NT, NT, 0, stream>>>(rows0, cols0, vals0,
                                                     rows1, cols1, vals1,
                                                     rows2, cols2, vals2,
                                                     curb, colb, valb);
    mcbuild_kernel<<<DIM / RPB, NT, 0, stream>>>(offb, colb, valb, Mc);

    (void)hipFuncSetAttribute((const void*)gemm8,
                              hipFuncAttributeMaxDynamicSharedMemorySize, GEMM_LDS);
    gemm8<<<256, 512, GEMM_LDS, stream>>>(Xb, Mc, bias, out);
}